// Round 10
// baseline (952.519 us; speedup 1.0000x reference)
//
#include <hip/hip_runtime.h>

// OmniMambaBlock — round 19: fuse k_inter + k_gout (identical t-tiling) into
// k_intergout. YB (16MB write + 16MB read per run) never touches HBM: inter
// results stay in regs, deposited per-K-half into a 33KB LDS tile consumed by
// gout staging. Ws LDS staging dropped (WoT read direct from global, L2-hot).
// 2 blocks/CU kept (peak LDS ~71KB). -192MB traffic, -6 launches. Numerics
// bit-identical. Everything else = round 18 (910us best).

typedef unsigned short u16;
typedef unsigned int   u32;
typedef __attribute__((ext_vector_type(8))) short short8;      // bf16x8
typedef __attribute__((ext_vector_type(8))) _Float16 half8;    // fp16x8
typedef __attribute__((ext_vector_type(4))) float f32x4;

#define LSEQ 32768
#define CDIM 128
#define NPROJ 644
#define ZXS 672
#define CCH 384
#define DIN 256
#define NHD 4
#define CKL 128
#define NCHK 256

__device__ __forceinline__ float b2f(u16 u){ u32 x=((u32)u)<<16; float f; __builtin_memcpy(&f,&x,4); return f; }
__device__ __forceinline__ u16 f2b(float f){ u32 x; __builtin_memcpy(&x,&f,4); x += 0x7fffu + ((x>>16)&1u); return (u16)(x>>16); }
__device__ __forceinline__ u16 f2h(float v){ _Float16 h=(_Float16)v; u16 b; __builtin_memcpy(&b,&h,2); return b; }
__device__ __forceinline__ float h2f(u16 b){ _Float16 h; __builtin_memcpy(&h,&b,2); return (float)h; }
__device__ __forceinline__ void up4(uint2 v, float* o){
  union { uint2 u; _Float16 h[4]; } c; c.u = v;
  o[0]=(float)c.h[0]; o[1]=(float)c.h[1]; o[2]=(float)c.h[2]; o[3]=(float)c.h[3];
}
__device__ __forceinline__ uint2 pk4(const float* o){
  union { uint2 u; _Float16 h[4]; } c;
  c.h[0]=(_Float16)o[0]; c.h[1]=(_Float16)o[1]; c.h[2]=(_Float16)o[2]; c.h[3]=(_Float16)o[3];
  return c.u;
}
__device__ __forceinline__ float sigmoidf_(float v){ return 1.f/(1.f+__expf(-v)); }
__device__ __forceinline__ float siluf_(float v){ return v*sigmoidf_(v); }
__device__ __forceinline__ float softplusf_(float v){ return (v>20.f)? v : log1pf(__expf(v)); }

__device__ __forceinline__ int seq2sp(int t, int run){
  int te = (run&1) ? (LSEQ-1-t) : t;
  int a = te>>10, b=(te>>5)&31, c=te&31;
  int d,h,w;
  switch(run>>1){
    case 0: d=a; h=b; w=c; break;
    case 1: h=a; d=b; w=c; break;
    default: w=a; d=b; h=c; break;
  }
  return (d<<10)|(h<<5)|w;
}

// -------- K1: xn = rmsnorm(x, norm_w) (c,s) + fused gate softmax (j,s) ------
__global__ void k_xn(const float* __restrict__ x, const float* __restrict__ nw,
                     const float* __restrict__ gw, const float* __restrict__ gb,
                     float* __restrict__ XN, float* __restrict__ G){
  int s = blockIdx.x*256 + threadIdx.x;
  float ss = 0.f;
  #pragma unroll 8
  for (int c=0;c<CDIM;c++){ float v=x[c*LSEQ+s]; ss += v*v; }
  float sc = rsqrtf(ss*(1.f/CDIM)+1e-6f);
  float a[6];
  #pragma unroll
  for (int j=0;j<6;j++) a[j]=gb[j];
  #pragma unroll 8
  for (int c=0;c<CDIM;c++){
    float v = x[c*LSEQ+s]*sc*nw[c];
    XN[c*LSEQ+s] = v;
    #pragma unroll
    for (int j=0;j<6;j++) a[j] += v*gw[c*6+j];
  }
  float m=a[0];
  #pragma unroll
  for (int j=1;j<6;j++) m = fmaxf(m,a[j]);
  float e[6], ssum=0.f;
  #pragma unroll
  for (int j=0;j<6;j++){ e[j]=__expf(a[j]-m); ssum+=e[j]; }
  float inv = 1.f/ssum;
  #pragma unroll
  for (int j=0;j<6;j++) G[j*LSEQ+s] = e[j]*inv;
}

// -------- K_permprep: XNT transpose + WinT/WoT prep (grid-split) ------------
__global__ __launch_bounds__(256) void k_permprep(const float* __restrict__ XN, u16* __restrict__ XNT, int dir,
                                                  const float* __restrict__ Win, const float* __restrict__ Wout,
                                                  u16* __restrict__ WinT, u16* __restrict__ WoT){
  __shared__ u16 TS[128*34];
  int bid = blockIdx.x;
  int tid = threadIdx.x;
  if (bid < 1024){
    int a = bid>>5, b = bid&31;
    int spa = (dir==1)? b : a;
    int spb = (dir==1)? a : b;
    int spbase = spa*1024 + spb*32;
    for (int idx=tid; idx<4096; idx+=256){
      int c = idx>>5, i = idx&31;
      TS[c*34+i] = f2b(XN[c*LSEQ + spbase + i]);
    }
    __syncthreads();
    for (int idx=tid; idx<4096; idx+=256){
      int i = idx>>7, c = idx&127;
      int t = (dir==2) ? (i*1024 + a*32 + b) : (a*1024 + b*32 + i);
      XNT[t*128 + c] = TS[c*34+i];
    }
  } else if (bid < 1408){
    int idx = (bid-1024)*256 + tid;
    int j = idx>>7, k = idx&127;
    float v = (j<NPROJ)? Win[k*NPROJ + j] : 0.f;
    WinT[idx] = f2b(v);
  } else {
    int idx = (bid-1408)*256 + tid;
    int c = idx>>8, k = idx&255;
    WoT[idx] = f2h(Wout[k*CDIM + c]);
  }
}

// ---------------- K2: ZX[t,j] = XNT[t,:]·WinT[j,:]  (bf16 MFMA, fp16 out) ---
__global__ __launch_bounds__(256) void k_gin_mfma(const u16* __restrict__ XNT, const u16* __restrict__ WinT,
                                                  u16* __restrict__ ZX, int flip){
  __shared__ u16 Asb[128*136];
  __shared__ u16 Bsb[128*136];
  int g = blockIdx.x;
  int w = (g&7)*192 + (g>>3);
  int by = w/6, bx = w - by*6;
  int j0 = bx*128, t0 = by*128;
  int tid = threadIdx.x;
  for (int ch = tid; ch < 2048; ch += 256){
    int row = ch>>4, c8 = ch&15;
    int tg = flip ? (LSEQ-1-(t0+row)) : (t0+row);
    uint4 av = *(const uint4*)(XNT + tg*128 + c8*8);
    *(uint4*)(&Asb[row*136 + c8*8]) = av;
    uint4 bv = *(const uint4*)(WinT + (j0+row)*128 + c8*8);
    *(uint4*)(&Bsb[row*136 + c8*8]) = bv;
  }
  __syncthreads();
  int lane = tid&63, wid = tid>>6;
  int wm = (wid>>1)*64, wn = (wid&1)*64;
  int lm = lane&15, lq = lane>>4;
  f32x4 acc[4][4] = {};
  for (int kt=0; kt<4; kt++){
    short8 af[4], bf[4];
    #pragma unroll
    for (int mt=0;mt<4;mt++) af[mt] = *(const short8*)(&Asb[(wm+mt*16+lm)*136 + kt*32 + lq*8]);
    #pragma unroll
    for (int nt=0;nt<4;nt++) bf[nt] = *(const short8*)(&Bsb[(wn+nt*16+lm)*136 + kt*32 + lq*8]);
    #pragma unroll
    for (int mt=0;mt<4;mt++)
      #pragma unroll
      for (int nt=0;nt<4;nt++)
        acc[mt][nt] = __builtin_amdgcn_mfma_f32_16x16x32_bf16(af[mt], bf[nt], acc[mt][nt], 0,0,0);
  }
  __syncthreads();   // MFMA reads of Asb done -> reuse as output tile
  #pragma unroll
  for (int mt=0;mt<4;mt++)
    #pragma unroll
    for (int nt=0;nt<4;nt++)
      #pragma unroll
      for (int r=0;r<4;r++)
        Asb[(wm+mt*16+lq*4+r)*136 + wn+nt*16+lm] = f2h(acc[mt][nt][r]);
  __syncthreads();
  if (bx < 5){
    for (int idx=tid; idx<2048; idx+=256){
      int row = idx>>4, q = idx&15;
      *(uint4*)(ZX + (t0+row)*ZXS + j0 + q*8) = *(const uint4*)(&Asb[row*136 + q*8]);
    }
  } else {
    // last j-tile: only 4 valid columns (j 640..643)
    for (int idx=tid; idx<128; idx+=256){
      *(uint2*)(ZX + (t0+idx)*ZXS + j0) = *(const uint2*)(&Asb[idx*136]);
    }
  }
}

// ---- K3: merged causal dwconv1d+silu (bids<1024) and dt cumsum (bids>=1024) -
__global__ __launch_bounds__(384) void k_convdt(const u16* __restrict__ ZX, const float* __restrict__ cw,
                                                const float* __restrict__ cb, u16* __restrict__ XB,
                                                const float* __restrict__ dtb, const float* __restrict__ Alog,
                                                float* __restrict__ DT, float* __restrict__ CUM,
                                                float* __restrict__ CDEC, float* __restrict__ DE){
  __shared__ u16 smc[35*384];
  int bid = blockIdx.x;
  int tid = threadIdx.x;
  if (bid < 1024){
    int t0 = bid*32;
    for (int idx=tid; idx<13440; idx+=384){
      int j = idx/384, chh = idx - j*384;
      int t = t0-3+j;
      smc[idx] = (t>=0)? ZX[t*ZXS + 256 + chh] : (u16)0;
    }
    __syncthreads();
    int ch = tid;
    float w0=cw[ch*4], w1=cw[ch*4+1], w2=cw[ch*4+2], w3=cw[ch*4+3], bb=cb[ch];
    for (int i=0;i<32;i++){
      float acc = w0*h2f(smc[i*384+ch]) + w1*h2f(smc[(i+1)*384+ch])
                + w2*h2f(smc[(i+2)*384+ch]) + w3*h2f(smc[(i+3)*384+ch]) + bb;
      XB[(t0+i)*CCH + ch] = f2h(siluf_(acc));
    }
  } else if (tid < 256){
    int g = (bid-1024)*4 + (tid>>6);
    int lane = tid&63;
    int c = g>>2, h = g&3;
    float A = -__expf(Alog[h]);
    float bias = dtb[h];
    int t0 = c*CKL + lane*2;
    float x0 = h2f(ZX[t0*ZXS + 640 + h]);
    float x1 = h2f(ZX[(t0+1)*ZXS + 640 + h]);
    float d0 = softplusf_(x0+bias), d1 = softplusf_(x1+bias);
    DT[t0*4+h] = d0; DT[(t0+1)*4+h] = d1;
    float e0 = d0*A, e1 = d1*A;
    float s = e0+e1;
    #pragma unroll
    for (int off=1; off<64; off<<=1){
      float v = __shfl_up(s, off, 64);
      if (lane>=off) s += v;
    }
    float c0 = s - e1, c1 = s;
    CUM[t0*4+h] = c0;
    CUM[(t0+1)*4+h] = c1;
    float tot = __shfl(s, 63, 64);
    DE[t0*4+h]     = __expf(tot - c0);
    DE[(t0+1)*4+h] = __expf(tot - c1);
    if (lane==0) CDEC[c*4+h] = __expf(tot);
  }
}

// ---------------- K4: per (chunk,head) — 39936 B LDS, 4 barriers ------------
__global__ __launch_bounds__(256,4) void k_chunk(const u16* __restrict__ XB, const float* __restrict__ DT,
                                                 const float* __restrict__ CUM, const float* __restrict__ DE,
                                                 const float* __restrict__ Dp,
                                                 u16* __restrict__ YA, u16* __restrict__ ST){
  __shared__ u16 sh[19968];
  u16* R0   = sh;            // BdeT[64][136] (phase A-B)
  u16* Mtri = sh;            // 11264 u16 triangular (phase G)
  u16* Xsh  = sh + 11264;    // [64][136]
  u16* scr  = sh;            // [128][68] Y staging (phase H)

  int bid = blockIdx.x; int c = bid&255, h = bid>>8;
  int tid = threadIdx.x, lane = tid&63, wid = tid>>6;
  int lm = lane&15, lq = lane>>4;
  const u16* XBc = XB + c*CKL*CCH;
  const float* DTc = DT + c*CKL*4 + h;
  const float* DEc = DE + c*CKL*4 + h;

  // ---- phase A: stage Xsh (xdt^T) + BdeT (B^T * de), u32-packed t-pairs ----
  for (int idx=tid; idx<4096; idx+=256){
    int t2 = idx>>6, n = idx&63, t = t2*2;
    const u16* r0 = XBc + t*CCH;
    float dt0 = DTc[t*4], dt1 = DTc[(t+1)*4];
    u32 xp = (u32)f2h(h2f(r0[(h<<6)+n])*dt0) | ((u32)f2h(h2f(r0[CCH+(h<<6)+n])*dt1)<<16);
    *(u32*)&Xsh[n*136 + t] = xp;
    float de0 = DEc[t*4], de1 = DEc[(t+1)*4];
    u32 bp = (u32)f2h(h2f(r0[256+n])*de0) | ((u32)f2h(h2f(r0[CCH+256+n])*de1)<<16);
    *(u32*)&R0[n*136 + t] = bp;
  }
  if (tid<128) ((float*)(Xsh + (tid>>1)*136 + 128))[tid&1] = CUM[(c*CKL+tid)*4 + h];
  __syncthreads();   // bar1
  #define CUMS(t) (((const float*)(Xsh + ((t)>>1)*136 + 128))[(t)&1])

  // ---- phase B: S = xdt^T @ (B*de)^T (LDS) ; CB = C·B^T (global reads) -----
  f32x4 sa[4] = {};
  #pragma unroll
  for (int kt=0; kt<4; kt++){
    half8 aa = *(const half8*)&Xsh[(wid*16+lm)*136 + kt*32 + lq*8];
    #pragma unroll
    for (int nt=0;nt<4;nt++){
      half8 bq = *(const half8*)&R0[(nt*16+lm)*136 + kt*32 + lq*8];
      sa[nt] = __builtin_amdgcn_mfma_f32_16x16x32_f16(aa, bq, sa[nt], 0,0,0);
    }
  }
  #pragma unroll
  for (int nt=0;nt<4;nt++){
    int n = nt*16 + lm;
    #pragma unroll
    for (int r=0;r<4;r++){
      int p = wid*16 + lq*4 + r;
      ST[((c*4+h)*64 + p)*64 + n] = f2h(sa[nt][r]);
    }
  }

  // CB with balanced strips {wid, 7-wid}; operands straight from XB (L1/L2-hot)
  int sp0 = wid, sp1 = 7 - wid;
  f32x4 cbA[4] = {};
  f32x4 cbB[8] = {};
  const u16* lanebase = XBc + lm*CCH + lq*8;
  #pragma unroll
  for (int kt=0; kt<2; kt++){
    half8 afA = *(const half8*)(lanebase + sp0*16*CCH + 320 + kt*32);
    half8 afB = *(const half8*)(lanebase + sp1*16*CCH + 320 + kt*32);
    #pragma unroll
    for (int st=0; st<8; st++){
      if (st <= sp1){
        half8 bq = *(const half8*)(lanebase + st*16*CCH + 256 + kt*32);
        if (st <= sp0)
          cbA[st&3] = __builtin_amdgcn_mfma_f32_16x16x32_f16(afA, bq, cbA[st&3], 0,0,0);
        cbB[st] = __builtin_amdgcn_mfma_f32_16x16x32_f16(afB, bq, cbB[st], 0,0,0);
      }
    }
  }
  __syncthreads();   // bar2: BdeT dead -> Mtri may overlay

  // ---- phase G: per-strip M build (wave-private) + Y_intra; results to regs -
  float dval = Dp[h];
  u16 outv[2][4][4];
  #pragma unroll
  for (int i=0;i<2;i++){
    int sp_ = i ? sp1 : sp0;
    int q = sp_ >> 1;
    int Wst = 32*q + 40;                                  // row width (u16), incl. 8 pad
    int mb  = 16*(32*q*q + 48*q + (sp_&1)*(32*q+40));     // strip base (u16)
    u16* Mrow = Mtri + mb;
    float ct[4];
    #pragma unroll
    for (int r=0;r<4;r++) ct[r] = CUMS(sp_*16 + lq*4 + r);

    // M[t][s] = cb * exp(cum_t - cum_s), lower-triangular
    #pragma unroll
    for (int st=0; st<8; st++){
      if (st <= sp_){
        int s = st*16 + lm;
        float cs = CUMS(s);
        f32x4 cb;
        if (i==0) cb = cbA[st&3]; else cb = cbB[st];
        if (st == sp_){
          #pragma unroll
          for (int r=0;r<4;r++){
            int t = sp_*16 + lq*4 + r;
            float m = (s <= t) ? cb[r]*__expf(ct[r]-cs) : 0.f;
            Mrow[(lq*4+r)*Wst + s] = f2h(m);
          }
          if (!(sp_&1)){   // zero the beyond-diagonal half of the last K=32 tile
            #pragma unroll
            for (int r=0;r<4;r++) Mrow[(lq*4+r)*Wst + s + 16] = 0;
          }
        } else {
          #pragma unroll
          for (int r=0;r<4;r++)
            Mrow[(lq*4+r)*Wst + s] = f2h(cb[r]*__expf(ct[r]-cs));
        }
      }
    }

    // Y_intra = M @ xdt (K tiles up to diagonal)
    f32x4 ya[4] = {};
    int nkt = q + 1;
    #pragma unroll
    for (int kt=0; kt<4; kt++){
      if (kt < nkt){
        half8 af = *(const half8*)&Mrow[lm*Wst + kt*32 + lq*8];
        #pragma unroll
        for (int nt=0;nt<4;nt++){
          half8 bq = *(const half8*)&Xsh[(nt*16+lm)*136 + kt*32 + lq*8];
          ya[nt] = __builtin_amdgcn_mfma_f32_16x16x32_f16(af, bq, ya[nt], 0,0,0);
        }
      }
    }

    // + D*xh, pack fp16 to regs
    #pragma unroll
    for (int nt=0;nt<4;nt++){
      int p = nt*16 + lm;
      #pragma unroll
      for (int r=0;r<4;r++){
        int t = sp_*16 + lq*4 + r;
        float xhv = h2f(XBc[t*CCH + (h<<6) + p]);
        outv[i][nt][r] = f2h(ya[nt][r] + dval*xhv);
      }
    }
  }
  __syncthreads();   // bar3: Xsh/Mtri reads done -> scr overlay

  // ---- phase H: stage [t][p] and write coalesced 128B rows -----------------
  #pragma unroll
  for (int i=0;i<2;i++){
    int sp_ = i ? sp1 : sp0;
    #pragma unroll
    for (int nt=0;nt<4;nt++)
      #pragma unroll
      for (int r=0;r<4;r++)
        scr[(sp_*16+lq*4+r)*68 + nt*16+lm] = outv[i][nt][r];
  }
  __syncthreads();   // bar4
  for (int idx=tid; idx<2048; idx+=256){
    int row = idx>>4, q = idx&15;
    *(uint2*)(YA + ((c*CKL+row)<<8) + (h<<6) + q*4) = *(const uint2*)(&scr[row*68 + q*4]);
  }
  #undef CUMS
}

// ---------------- K5: block-local segmented scan ----------------------------
__global__ __launch_bounds__(256) void k_scan(const u16* __restrict__ ST, u16* __restrict__ HP,
                                              const float* __restrict__ CDEC){
  __shared__ float L[4][64][64];   // 65536 B local prefixes
  __shared__ float E[4][64];       // segment-end values
  int tid = threadIdx.x;
  int j = tid>>6, s = tid&63;
  int b = blockIdx.x;
  int g = b*64 + s;
  int h = g>>12;
  int a = j*64;
  float hloc = 0.f;
  #pragma unroll 16
  for (int i=0;i<64;i++){
    int c = a+i;
    L[j][i][s] = hloc;
    hloc = CDEC[(c<<2)+h]*hloc + h2f(ST[g + (c<<14)]);
  }
  E[j][s] = hloc;
  __syncthreads();
  float carry = 0.f;
  for (int k=0;k<j;k++){           // wave-uniform trip count (j = wave id)
    float P = 1.f;
    #pragma unroll 16
    for (int i=0;i<64;i++) P *= CDEC[((k*64+i)<<2)+h];
    carry = E[k][s] + P*carry;
  }
  float m = 1.f;
  #pragma unroll 16
  for (int i=0;i<64;i++){
    int c = a+i;
    HP[g + (c<<14)] = f2h(L[j][i][s] + m*carry);
    m *= CDEC[(c<<2)+h];
  }
}

// -------- K6: fused inter (YB in LDS) + ynorm + out GEMM + gate scatter -----
// Block c covers t rows [128c, 128c+128) — identical tiling for both halves.
// Phase 1: stage Cs/Hs/ex; inter MFMA per-head into regs (iacc[8][4]).
// YB tile lives only in LDS: waves 0,1 deposit cols 0..127 (heads 0,1) for
// kb=0; waves 2,3 deposit heads 2,3 during kb=0's MFMA for kb=1.
// Gout B-operand (WoT) read direct from global (64KB, L2-hot). 2 blocks/CU.
__global__ __launch_bounds__(256,2) void k_intergout(const u16* __restrict__ XB, const float* __restrict__ CUM,
                                                     const u16* __restrict__ HP,
                                                     const u16* __restrict__ YA, const u16* __restrict__ ZX,
                                                     const float* __restrict__ nw, const u16* __restrict__ WoT,
                                                     const float* __restrict__ G, float* __restrict__ GACC, int run){
  __shared__ u16 sh[34304];        // phase1: Cs[9216]+Hs[18432]; phase2: Ybs[16896]+Ys[17408]
  __shared__ float ex_s[512];
  __shared__ float SSs[128];
  u16* Cs  = sh;                   // [128][72]
  u16* Hs  = sh + 9216;            // [4*64][72]
  u16* Ybs = sh;                   // [128][132] (stride 132 -> <=2-way on uint2 reads)
  u16* Ys  = sh + 16896;           // [128][136]
  int c = blockIdx.x;
  int tid = threadIdx.x, lane = tid&63, wid = tid>>6;
  int lm = lane&15, lq = lane>>4;
  int t0 = c*CKL;

  // ---- phase 1: stage C/H/ex ----
  for (int idx=tid; idx<1024; idx+=256){
    int t = idx>>3, b8 = idx&7;
    *(uint4*)&Cs[t*72 + b8*8] = *(const uint4*)(XB + (t0+t)*CCH + 320 + b8*8);
  }
  for (int idx=tid; idx<2048; idx+=256){
    int h = idx>>9, p = (idx>>3)&63, b8 = idx&7;
    *(uint4*)&Hs[(h*64+p)*72 + b8*8] = *(const uint4*)(HP + ((c*4+h)*64+p)*64 + b8*8);
  }
  for (int idx=tid; idx<512; idx+=256){
    int h = idx>>7, t = idx&127;
    ex_s[h*128+t] = __expf(CUM[(t0+t)*4+h]);
  }
  __syncthreads();   // bar1

  // ---- inter MFMA: wave owns head h=wid ----
  {
    const u16* Hh = &Hs[wid*64*72];
    f32x4 iacc[8][4] = {};
    for (int kt=0; kt<2; kt++){
      half8 af[8], bfv[4];
      #pragma unroll
      for (int mt=0;mt<8;mt++) af[mt] = *(const half8*)&Cs[(mt*16+lm)*72 + kt*32 + lq*8];
      #pragma unroll
      for (int nt=0;nt<4;nt++) bfv[nt] = *(const half8*)&Hh[(nt*16+lm)*72 + kt*32 + lq*8];
      #pragma unroll
      for (int mt=0;mt<8;mt++)
        #pragma unroll
        for (int nt=0;nt<4;nt++)
          iacc[mt][nt] = __builtin_amdgcn_mfma_f32_16x16x32_f16(af[mt], bfv[nt], iacc[mt][nt], 0,0,0);
    }
    __syncthreads();   // bar2: Cs/Hs reads done -> Ybs/Ys overlay

    // ---- waves 0,1 deposit heads 0,1 (Ybs cols 0..127) ----
    if (wid < 2){
      #pragma unroll
      for (int mt=0;mt<8;mt++){
        #pragma unroll
        for (int r=0;r<4;r++){
          int t = mt*16 + lq*4 + r;
          float e = ex_s[wid*128+t];
          #pragma unroll
          for (int nt=0;nt<4;nt++)
            Ybs[t*132 + wid*64 + nt*16+lm] = f2h(e*iacc[mt][nt][r]);
        }
      }
    }
    __syncthreads();   // bar3

    // ---- gout: 2 K-halves; YB from LDS, WoT from global ----
    f32x4 acc[2][8] = {};
    for (int kb=0; kb<2; kb++){
      for (int ch=tid; ch<2048; ch+=256){
        int row = ch>>4, c8 = ch&15;
        int t = t0+row;
        int cb = kb*128 + c8*8;
        uint2 av0 = *(const uint2*)(YA + t*DIN + cb);
        uint2 av1 = *(const uint2*)(YA + t*DIN + cb + 4);
        uint2 bv0 = *(const uint2*)&Ybs[row*132 + c8*8];
        uint2 bv1 = *(const uint2*)&Ybs[row*132 + c8*8 + 4];
        uint2 zv0 = *(const uint2*)(ZX + t*ZXS + cb);
        uint2 zv1 = *(const uint2*)(ZX + t*ZXS + cb + 4);
        float af[8], bf[8], zf[8];
        up4(av0, af); up4(av1, af+4);
        up4(bv0, bf); up4(bv1, bf+4);
        up4(zv0, zf); up4(zv1, zf+4);
        float ssp = 0.f;
        union { uint4 u; u16 h[8]; } pk;
        #pragma unroll
        for (int j=0;j<8;j++){
          float u = (af[j]+bf[j])*siluf_(zf[j]);
          ssp += u*u;
          pk.h[j] = f2h(u*nw[cb+j]);
        }
        *(uint4*)&Ys[row*136 + c8*8] = pk.u;
        #pragma unroll
        for (int off=1; off<16; off<<=1) ssp += __shfl_xor(ssp, off, 64);
        if ((lane&15)==0){ if (kb==0) SSs[row] = ssp; else SSs[row] += ssp; }
      }
      __syncthreads();   // bar4 / bar6: Ys staged (and, kb=1: Ybs heads 2,3 ready)
      for (int kt=0; kt<4; kt++){
        half8 af[2], bfv[8];
        #pragma unroll
        for (int mt=0;mt<2;mt++) af[mt] = *(const half8*)&Ys[(wid*32+mt*16+lm)*136 + kt*32 + lq*8];
        #pragma unroll
        for (int nt=0;nt<8;nt++) bfv[nt] = *(const half8*)(WoT + (nt*16+lm)*DIN + kb*128 + kt*32 + lq*8);
        #pragma unroll
        for (int mt=0;mt<2;mt++)
          #pragma unroll
          for (int nt=0;nt<8;nt++)
            acc[mt][nt] = __builtin_amdgcn_mfma_f32_16x16x32_f16(af[mt], bfv[nt], acc[mt][nt], 0,0,0);
      }
      if (kb==0){
        // waves 2,3 deposit heads 2,3 (overwrite Ybs cols 0..127) for kb=1
        if (wid >= 2){
          #pragma unroll
          for (int mt=0;mt<8;mt++){
            #pragma unroll
            for (int r=0;r<4;r++){
              int t = mt*16 + lq*4 + r;
              float e = ex_s[wid*128+t];
              #pragma unroll
              for (int nt=0;nt<4;nt++)
                Ybs[t*132 + (wid-2)*64 + nt*16+lm] = f2h(e*iacc[mt][nt][r]);
            }
          }
        }
        __syncthreads();   // bar5: Ys reads done + Ybs refreshed
      }
    }

    // ---- epilogue: rmsnorm scale + gate scatter into GACC ----
    #pragma unroll
    for (int mt=0;mt<2;mt++){
      #pragma unroll
      for (int r=0;r<4;r++){
        int tl = wid*32 + mt*16 + lq*4 + r;
        int t = t0 + tl;
        int sp = seq2sp(t, run);
        float sc = rsqrtf(SSs[tl]*(1.f/DIN)+1e-6f);
        float g = G[run*LSEQ + sp] * sc;
        float* dst = &GACC[sp*CDIM];
        if (run==0){
          #pragma unroll
          for (int nt=0;nt<8;nt++) dst[nt*16+lm] = g*acc[mt][nt][r];
        } else {
          #pragma unroll
          for (int nt=0;nt<8;nt++) dst[nt*16+lm] += g*acc[mt][nt][r];
        }
      }
    }
  }
}

// ---------------- K8: depthwise 3x3x3 conv, LDS-tiled -----------------------
__global__ __launch_bounds__(256) void k_dwconv(const float* __restrict__ XN, const float* __restrict__ w,
                                                const float* __restrict__ b, float* __restrict__ LC1){
  __shared__ float sm[3*34*40];
  int cc = blockIdx.x>>5, d = blockIdx.x&31;
  int tid = threadIdx.x;
  for (int i=tid; i<4080; i+=256) sm[i] = 0.f;
  __syncthreads();
  #pragma unroll
  for (int p=0;p<3;p++){
    int dz = d-1+p;
    if ((unsigned)dz<=31u){
      for (int idx=tid; idx<1024; idx+=256){
        int hh = idx>>5, ww = idx&31;
        sm[p*1360 + (hh+1)*40 + (ww+4)] = XN[cc*LSEQ + (dz<<10) + idx];
      }
    }
  }
  __syncthreads();
  float wreg[27];
  #pragma unroll
  for (int i=0;i<27;i++) wreg[i] = w[cc*27+i];
  float bias = b[cc];
  int h = tid>>3, w0 = (tid&7)*4;
  float4 acc = {bias,bias,bias,bias};
  #pragma unroll
  for (int p=0;p<3;p++){
    #pragma unroll
    for (int dy=0;dy<3;dy++){
      const float* row = &sm[p*1360 + (h+dy)*40 + 4];
      float left  = row[w0-1];
      float4 mid  = *(const float4*)&row[w0];
      float right = row[w0+4];
      float wa=wreg[p*9+dy*3+0], wb=wreg[p*9+dy*3+1], wc=wreg[p*9+dy*3+2];
      acc.x += wa*left  + wb*mid.x + wc*mid.y;
      acc.y += wa*mid.x + wb*mid.y + wc*mid.z;
      acc.z += wa*mid.y + wb*mid.z + wc*mid.w;
      acc.w += wa*mid.z + wb*mid.w + wc*right;
    }
  }
  *(float4*)&LC1[cc*LSEQ + (d<<10) + h*32 + w0] = acc;
}

// ---------------- K9: pointwise 128x128 + silu (fp16 MFMA) ------------------
__global__ __launch_bounds__(256) void k_pw(const float* __restrict__ LC1, const float* __restrict__ pw,
                                            const float* __restrict__ pwb, float* __restrict__ LC2){
  __shared__ u16 Ws[128*136];
  __shared__ u16 Bs[128*136];
  int s0 = blockIdx.x*128;
  int tid = threadIdx.x, lane = tid&63, wid = tid>>6;
  int lm = lane&15, lq = lane>>4;
  for (int idx=tid; idx<16384; idx+=256){
    int o = idx>>7, cc = idx&127;
    Ws[o*136+cc] = f2h(pw[idx]);
  }
  for (int idx=tid; idx<16384; idx+=256){
    int cc = idx>>7, n = idx&127;
    Bs[n*136+cc] = f2h(LC1[cc*LSEQ + s0 + n]);
  }
  __syncthreads();
  f32x4 acc[2][8] = {};
  for (int kt=0; kt<4; kt++){
    half8 af[2], bfv[8];
    #pragma unroll
    for (int mt=0;mt<2;mt++) af[mt] = *(const half8*)&Ws[(wid*32+mt*16+lm)*136 + kt*32 + lq*8];
    #pragma unroll
    for (int nt=0;nt<8;nt++) bfv[nt] = *(const half8*)&Bs[(nt*16+lm)*136 + kt*32 + lq*8];
    #pragma unroll
    for (int mt=0;mt<2;mt++)
      #pragma unroll
      for (int nt=0;nt<8;nt++)
        acc[mt][nt] = __builtin_amdgcn_mfma_f32_16x16x32_f16(af[mt], bfv[nt], acc[mt][nt], 0,0,0);
  }
  #pragma unroll
  for (int mt=0;mt<2;mt++){
    #pragma unroll
    for (int r=0;r<4;r++){
      int o = wid*32 + mt*16 + lq*4 + r;
      float bb = pwb[o];
      float* dst = &LC2[o*LSEQ + s0];
      #pragma unroll
      for (int nt=0;nt<8;nt++){
        int n = nt*16 + lm;
        dst[n] = siluf_(acc[mt][nt][r] + bb);
      }
    }
  }
}

// -------- K10: fused = a*g + (1-a)*lc, transpose + per-block mean partials --
__global__ void k_fuse(const float* __restrict__ GACC, const float* __restrict__ LC2,
                       const float* __restrict__ alpha, float* __restrict__ FUSED,
                       float* __restrict__ MEANP){
  __shared__ float tile[64*65];
  int bs = blockIdx.x>>1, bc = blockIdx.x&1;
  int s0 = bs*64, c0 = bc*64;
  int tid = threadIdx.x;
  float a = alpha[0];
  for (int idx=tid; idx<4096; idx+=256){
    int i = idx>>6, j = idx&63;
    tile[i*65+j] = GACC[(s0+i)*CDIM + c0+j];
  }
  __syncthreads();
  for (int idx=tid; idx<4096; idx+=256){
    int j = idx>>6, i = idx&63;   // j wave-uniform; i = lane
    float g = tile[i*65+j];
    float l = LC2[(c0+j)*LSEQ + s0+i];
    float f = a*g + (1.f-a)*l;
    FUSED[(c0+j)*LSEQ + s0+i] = f;
    float wsum = f;
    #pragma unroll
    for (int off=32; off; off>>=1) wsum += __shfl_xor(wsum, off, 64);
    if ((tid&63)==0) MEANP[(c0+j)*512 + bs] = wsum;
  }
}

// ---------------- K11: channel attention (reduces MEANP partials) -----------
__global__ void k_ca(const float* __restrict__ MEANP, const float* __restrict__ w1, const float* __restrict__ b1,
                     const float* __restrict__ w2, const float* __restrict__ b2, float* __restrict__ SIG){
  __shared__ float MEANsh[128];
  __shared__ float y1[8];
  int tid = threadIdx.x;
  {
    float acc = 0.f;
    const float* p = MEANP + tid*512;
    #pragma unroll 16
    for (int b=0;b<512;b++) acc += p[b];
    MEANsh[tid] = acc*(1.f/LSEQ);
  }
  __syncthreads();
  if (tid<8){
    float acc = b1[tid];
    for (int c=0;c<128;c++) acc += w1[tid*128+c]*MEANsh[c];
    y1[tid] = (acc>=0.f)? acc : 0.1f*acc;
  }
  __syncthreads();
  float acc = b2[tid];
  #pragma unroll
  for (int o=0;o<8;o++) acc += w2[tid*8+o]*y1[o];
  SIG[tid] = sigmoidf_(acc);
}

// ---------------- K12: out = x + fused * sigmoid(yc) ------------------------
__global__ void k_final(const float* __restrict__ x, const float* __restrict__ F, const float* __restrict__ SIG,
                        float* __restrict__ out){
  int idx = blockIdx.x*256 + threadIdx.x;
  int cc = idx>>15;
  out[idx] = x[idx] + F[idx]*SIG[cc];
}

extern "C" void kernel_launch(void* const* d_in, const int* in_sizes, int n_in,
                              void* d_out, int out_size, void* d_ws, size_t ws_size,
                              hipStream_t stream){
  (void)in_sizes; (void)n_in; (void)out_size; (void)ws_size;
  const float* x       = (const float*)d_in[0];
  const float* norm_w  = (const float*)d_in[1];
  const float* gate_w  = (const float*)d_in[2];
  const float* gate_b  = (const float*)d_in[3];
  const float* loc_dw_w= (const float*)d_in[28];
  const float* loc_dw_b= (const float*)d_in[29];
  const float* loc_pw_w= (const float*)d_in[30];
  const float* loc_pw_b= (const float*)d_in[31];
  const float* ca_w1   = (const float*)d_in[32];
  const float* ca_b1   = (const float*)d_in[33];
  const float* ca_w2   = (const float*)d_in[34];
  const float* ca_b2   = (const float*)d_in[35];
  const float* alpha   = (const float*)d_in[36];

  float* W     = (float*)d_ws;
  float* XN    = W;                         // 4,194,304
  float* GATES = XN    + 4194304;           //   196,608
  float* GACC  = GATES + 196608;            // 4,194,304
  u16*   ZX    = (u16*)(GACC + 4194304);    // 22,020,096 u16 (stride 672)
  u16*   XB    = (u16*)(GACC + 4194304 + 11010048);   // 12,582,912 u16
  float* DT    = GACC + 4194304 + 11010048 + 6291456; // 131,072
  float* CUM   = DT    + 131072;            //   131,072
  float* CDEC  = CUM   + 131072;            //     1,024
  float* DE    = CDEC  + 1024;              //   131,072
  float* STreg = DE    + 131072;            // 4,194,304 fl region (ST16)
  float* Y     = STreg + 4194304;           // 8,388,608 fl = YA fp16 (+ spare)
  float* LC1   = Y     + 8388608;           // 4,194,304 (HPREV16 alias)
  float* LC2   = LC1   + 4194304;           // 4,194,304
  float* MEANP = LC2   + 4194304;           //    65,536
  float* SIG   = MEANP + 65536;             //       128
  u16*   XNT   = (u16*)(SIG + 128);         // 4,194,304 u16
  u16*   WinT  = XNT + 4194304;             //    98,304 u16
  u16*   WoT   = WinT + 98304;              //    32,768 u16
  u16*   ST16  = (u16*)STreg;               // 4,194,304 u16
  u16*   YA    = (u16*)Y;                   // 8,388,608 u16
  u16*   HP16  = (u16*)LC1;                 // 4,194,304 u16

  k_xn<<<128,256,0,stream>>>(x, norm_w, gate_w, gate_b, XN, GATES);

  for (int r=0;r<6;r++){
    int m = r>>1;
    const float* Win   = (const float*)d_in[4 + m*8 + 0];
    const float* convw = (const float*)d_in[4 + m*8 + 1];
    const float* convb = (const float*)d_in[4 + m*8 + 2];
    const float* dtb   = (const float*)d_in[4 + m*8 + 3];
    const float* Alog  = (const float*)d_in[4 + m*8 + 4];
    const float* Dp    = (const float*)d_in[4 + m*8 + 5];
    const float* nw2   = (const float*)d_in[4 + m*8 + 6];
    const float* Wout  = (const float*)d_in[4 + m*8 + 7];
    if ((r&1)==0){
      k_permprep<<<1536,256,0,stream>>>(XN, XNT, m, Win, Wout, WinT, WoT);
    }
    k_gin_mfma<<<1536,256,0,stream>>>(XNT, WinT, ZX, r&1);
    k_convdt  <<<1280,384,0,stream>>>(ZX, convw, convb, XB, dtb, Alog, DT, CUM, CDEC, DE);
    k_chunk   <<<1024,256,0,stream>>>(XB, DT, CUM, DE, Dp, YA, ST16);
    k_scan    <<<256,256,0,stream>>>(ST16, HP16, CDEC);
    k_intergout<<<256,256,0,stream>>>(XB, CUM, HP16, YA, ZX, nw2, WoT, GATES, GACC, r);
  }

  k_dwconv<<<4096,256,0,stream>>>(XN, loc_dw_w, loc_dw_b, LC1);
  k_pw    <<<256,256,0,stream>>>(LC1, loc_pw_w, loc_pw_b, LC2);
  k_fuse  <<<1024,256,0,stream>>>(GACC, LC2, alpha, LC1, MEANP);
  k_ca    <<<1,128,0,stream>>>(MEANP, ca_w1, ca_b1, ca_w2, ca_b2, SIG);
  k_final <<<16384,256,0,stream>>>(x, LC1, SIG, (float*)d_out);
}

// Round 11
// 873.785 us; speedup vs baseline: 1.0901x; 1.0901x over previous
//
#include <hip/hip_runtime.h>

// OmniMambaBlock — round 20: revert round-19 fusion (1 block/CU serial chain,
// occupancy 9%). Back to round-18 structure (910us best) with ONE delta:
// k_inter and k_gout split into 64-row t-tiles (grid 256->512 each).
// k_inter ~47KB LDS, k_gout ~52.5KB -> 2 blocks resident/CU (was 1).
// Per-element MFMA sequences unchanged -> bit-identical numerics.

typedef unsigned short u16;
typedef unsigned int   u32;
typedef __attribute__((ext_vector_type(8))) short short8;      // bf16x8
typedef __attribute__((ext_vector_type(8))) _Float16 half8;    // fp16x8
typedef __attribute__((ext_vector_type(4))) float f32x4;

#define LSEQ 32768
#define CDIM 128
#define NPROJ 644
#define ZXS 672
#define CCH 384
#define DIN 256
#define NHD 4
#define CKL 128
#define NCHK 256

__device__ __forceinline__ float b2f(u16 u){ u32 x=((u32)u)<<16; float f; __builtin_memcpy(&f,&x,4); return f; }
__device__ __forceinline__ u16 f2b(float f){ u32 x; __builtin_memcpy(&x,&f,4); x += 0x7fffu + ((x>>16)&1u); return (u16)(x>>16); }
__device__ __forceinline__ u16 f2h(float v){ _Float16 h=(_Float16)v; u16 b; __builtin_memcpy(&b,&h,2); return b; }
__device__ __forceinline__ float h2f(u16 b){ _Float16 h; __builtin_memcpy(&h,&b,2); return (float)h; }
__device__ __forceinline__ void up4(uint2 v, float* o){
  union { uint2 u; _Float16 h[4]; } c; c.u = v;
  o[0]=(float)c.h[0]; o[1]=(float)c.h[1]; o[2]=(float)c.h[2]; o[3]=(float)c.h[3];
}
__device__ __forceinline__ uint2 pk4(const float* o){
  union { uint2 u; _Float16 h[4]; } c;
  c.h[0]=(_Float16)o[0]; c.h[1]=(_Float16)o[1]; c.h[2]=(_Float16)o[2]; c.h[3]=(_Float16)o[3];
  return c.u;
}
__device__ __forceinline__ float sigmoidf_(float v){ return 1.f/(1.f+__expf(-v)); }
__device__ __forceinline__ float siluf_(float v){ return v*sigmoidf_(v); }
__device__ __forceinline__ float softplusf_(float v){ return (v>20.f)? v : log1pf(__expf(v)); }

__device__ __forceinline__ int seq2sp(int t, int run){
  int te = (run&1) ? (LSEQ-1-t) : t;
  int a = te>>10, b=(te>>5)&31, c=te&31;
  int d,h,w;
  switch(run>>1){
    case 0: d=a; h=b; w=c; break;
    case 1: h=a; d=b; w=c; break;
    default: w=a; d=b; h=c; break;
  }
  return (d<<10)|(h<<5)|w;
}

// -------- K1: xn = rmsnorm(x, norm_w) (c,s) + fused gate softmax (j,s) ------
__global__ void k_xn(const float* __restrict__ x, const float* __restrict__ nw,
                     const float* __restrict__ gw, const float* __restrict__ gb,
                     float* __restrict__ XN, float* __restrict__ G){
  int s = blockIdx.x*256 + threadIdx.x;
  float ss = 0.f;
  #pragma unroll 8
  for (int c=0;c<CDIM;c++){ float v=x[c*LSEQ+s]; ss += v*v; }
  float sc = rsqrtf(ss*(1.f/CDIM)+1e-6f);
  float a[6];
  #pragma unroll
  for (int j=0;j<6;j++) a[j]=gb[j];
  #pragma unroll 8
  for (int c=0;c<CDIM;c++){
    float v = x[c*LSEQ+s]*sc*nw[c];
    XN[c*LSEQ+s] = v;
    #pragma unroll
    for (int j=0;j<6;j++) a[j] += v*gw[c*6+j];
  }
  float m=a[0];
  #pragma unroll
  for (int j=1;j<6;j++) m = fmaxf(m,a[j]);
  float e[6], ssum=0.f;
  #pragma unroll
  for (int j=0;j<6;j++){ e[j]=__expf(a[j]-m); ssum+=e[j]; }
  float inv = 1.f/ssum;
  #pragma unroll
  for (int j=0;j<6;j++) G[j*LSEQ+s] = e[j]*inv;
}

// -------- K_permprep: XNT transpose + WinT/WoT prep (grid-split) ------------
__global__ __launch_bounds__(256) void k_permprep(const float* __restrict__ XN, u16* __restrict__ XNT, int dir,
                                                  const float* __restrict__ Win, const float* __restrict__ Wout,
                                                  u16* __restrict__ WinT, u16* __restrict__ WoT){
  __shared__ u16 TS[128*34];
  int bid = blockIdx.x;
  int tid = threadIdx.x;
  if (bid < 1024){
    int a = bid>>5, b = bid&31;
    int spa = (dir==1)? b : a;
    int spb = (dir==1)? a : b;
    int spbase = spa*1024 + spb*32;
    for (int idx=tid; idx<4096; idx+=256){
      int c = idx>>5, i = idx&31;
      TS[c*34+i] = f2b(XN[c*LSEQ + spbase + i]);
    }
    __syncthreads();
    for (int idx=tid; idx<4096; idx+=256){
      int i = idx>>7, c = idx&127;
      int t = (dir==2) ? (i*1024 + a*32 + b) : (a*1024 + b*32 + i);
      XNT[t*128 + c] = TS[c*34+i];
    }
  } else if (bid < 1408){
    int idx = (bid-1024)*256 + tid;
    int j = idx>>7, k = idx&127;
    float v = (j<NPROJ)? Win[k*NPROJ + j] : 0.f;
    WinT[idx] = f2b(v);
  } else {
    int idx = (bid-1408)*256 + tid;
    int c = idx>>8, k = idx&255;
    WoT[idx] = f2h(Wout[k*CDIM + c]);
  }
}

// ---------------- K2: ZX[t,j] = XNT[t,:]·WinT[j,:]  (bf16 MFMA, fp16 out) ---
__global__ __launch_bounds__(256) void k_gin_mfma(const u16* __restrict__ XNT, const u16* __restrict__ WinT,
                                                  u16* __restrict__ ZX, int flip){
  __shared__ u16 Asb[128*136];
  __shared__ u16 Bsb[128*136];
  int g = blockIdx.x;
  int w = (g&7)*192 + (g>>3);
  int by = w/6, bx = w - by*6;
  int j0 = bx*128, t0 = by*128;
  int tid = threadIdx.x;
  for (int ch = tid; ch < 2048; ch += 256){
    int row = ch>>4, c8 = ch&15;
    int tg = flip ? (LSEQ-1-(t0+row)) : (t0+row);
    uint4 av = *(const uint4*)(XNT + tg*128 + c8*8);
    *(uint4*)(&Asb[row*136 + c8*8]) = av;
    uint4 bv = *(const uint4*)(WinT + (j0+row)*128 + c8*8);
    *(uint4*)(&Bsb[row*136 + c8*8]) = bv;
  }
  __syncthreads();
  int lane = tid&63, wid = tid>>6;
  int wm = (wid>>1)*64, wn = (wid&1)*64;
  int lm = lane&15, lq = lane>>4;
  f32x4 acc[4][4] = {};
  for (int kt=0; kt<4; kt++){
    short8 af[4], bf[4];
    #pragma unroll
    for (int mt=0;mt<4;mt++) af[mt] = *(const short8*)(&Asb[(wm+mt*16+lm)*136 + kt*32 + lq*8]);
    #pragma unroll
    for (int nt=0;nt<4;nt++) bf[nt] = *(const short8*)(&Bsb[(wn+nt*16+lm)*136 + kt*32 + lq*8]);
    #pragma unroll
    for (int mt=0;mt<4;mt++)
      #pragma unroll
      for (int nt=0;nt<4;nt++)
        acc[mt][nt] = __builtin_amdgcn_mfma_f32_16x16x32_bf16(af[mt], bf[nt], acc[mt][nt], 0,0,0);
  }
  __syncthreads();   // MFMA reads of Asb done -> reuse as output tile
  #pragma unroll
  for (int mt=0;mt<4;mt++)
    #pragma unroll
    for (int nt=0;nt<4;nt++)
      #pragma unroll
      for (int r=0;r<4;r++)
        Asb[(wm+mt*16+lq*4+r)*136 + wn+nt*16+lm] = f2h(acc[mt][nt][r]);
  __syncthreads();
  if (bx < 5){
    for (int idx=tid; idx<2048; idx+=256){
      int row = idx>>4, q = idx&15;
      *(uint4*)(ZX + (t0+row)*ZXS + j0 + q*8) = *(const uint4*)(&Asb[row*136 + q*8]);
    }
  } else {
    // last j-tile: only 4 valid columns (j 640..643)
    for (int idx=tid; idx<128; idx+=256){
      *(uint2*)(ZX + (t0+idx)*ZXS + j0) = *(const uint2*)(&Asb[idx*136]);
    }
  }
}

// ---- K3: merged causal dwconv1d+silu (bids<1024) and dt cumsum (bids>=1024) -
__global__ __launch_bounds__(384) void k_convdt(const u16* __restrict__ ZX, const float* __restrict__ cw,
                                                const float* __restrict__ cb, u16* __restrict__ XB,
                                                const float* __restrict__ dtb, const float* __restrict__ Alog,
                                                float* __restrict__ DT, float* __restrict__ CUM,
                                                float* __restrict__ CDEC, float* __restrict__ DE){
  __shared__ u16 smc[35*384];
  int bid = blockIdx.x;
  int tid = threadIdx.x;
  if (bid < 1024){
    int t0 = bid*32;
    for (int idx=tid; idx<13440; idx+=384){
      int j = idx/384, chh = idx - j*384;
      int t = t0-3+j;
      smc[idx] = (t>=0)? ZX[t*ZXS + 256 + chh] : (u16)0;
    }
    __syncthreads();
    int ch = tid;
    float w0=cw[ch*4], w1=cw[ch*4+1], w2=cw[ch*4+2], w3=cw[ch*4+3], bb=cb[ch];
    for (int i=0;i<32;i++){
      float acc = w0*h2f(smc[i*384+ch]) + w1*h2f(smc[(i+1)*384+ch])
                + w2*h2f(smc[(i+2)*384+ch]) + w3*h2f(smc[(i+3)*384+ch]) + bb;
      XB[(t0+i)*CCH + ch] = f2h(siluf_(acc));
    }
  } else if (tid < 256){
    int g = (bid-1024)*4 + (tid>>6);
    int lane = tid&63;
    int c = g>>2, h = g&3;
    float A = -__expf(Alog[h]);
    float bias = dtb[h];
    int t0 = c*CKL + lane*2;
    float x0 = h2f(ZX[t0*ZXS + 640 + h]);
    float x1 = h2f(ZX[(t0+1)*ZXS + 640 + h]);
    float d0 = softplusf_(x0+bias), d1 = softplusf_(x1+bias);
    DT[t0*4+h] = d0; DT[(t0+1)*4+h] = d1;
    float e0 = d0*A, e1 = d1*A;
    float s = e0+e1;
    #pragma unroll
    for (int off=1; off<64; off<<=1){
      float v = __shfl_up(s, off, 64);
      if (lane>=off) s += v;
    }
    float c0 = s - e1, c1 = s;
    CUM[t0*4+h] = c0;
    CUM[(t0+1)*4+h] = c1;
    float tot = __shfl(s, 63, 64);
    DE[t0*4+h]     = __expf(tot - c0);
    DE[(t0+1)*4+h] = __expf(tot - c1);
    if (lane==0) CDEC[c*4+h] = __expf(tot);
  }
}

// ---------------- K4: per (chunk,head) — 39936 B LDS, 4 barriers ------------
__global__ __launch_bounds__(256,4) void k_chunk(const u16* __restrict__ XB, const float* __restrict__ DT,
                                                 const float* __restrict__ CUM, const float* __restrict__ DE,
                                                 const float* __restrict__ Dp,
                                                 u16* __restrict__ YA, u16* __restrict__ ST){
  __shared__ u16 sh[19968];
  u16* R0   = sh;            // BdeT[64][136] (phase A-B)
  u16* Mtri = sh;            // 11264 u16 triangular (phase G)
  u16* Xsh  = sh + 11264;    // [64][136]
  u16* scr  = sh;            // [128][68] Y staging (phase H)

  int bid = blockIdx.x; int c = bid&255, h = bid>>8;
  int tid = threadIdx.x, lane = tid&63, wid = tid>>6;
  int lm = lane&15, lq = lane>>4;
  const u16* XBc = XB + c*CKL*CCH;
  const float* DTc = DT + c*CKL*4 + h;
  const float* DEc = DE + c*CKL*4 + h;

  // ---- phase A: stage Xsh (xdt^T) + BdeT (B^T * de), u32-packed t-pairs ----
  for (int idx=tid; idx<4096; idx+=256){
    int t2 = idx>>6, n = idx&63, t = t2*2;
    const u16* r0 = XBc + t*CCH;
    float dt0 = DTc[t*4], dt1 = DTc[(t+1)*4];
    u32 xp = (u32)f2h(h2f(r0[(h<<6)+n])*dt0) | ((u32)f2h(h2f(r0[CCH+(h<<6)+n])*dt1)<<16);
    *(u32*)&Xsh[n*136 + t] = xp;
    float de0 = DEc[t*4], de1 = DEc[(t+1)*4];
    u32 bp = (u32)f2h(h2f(r0[256+n])*de0) | ((u32)f2h(h2f(r0[CCH+256+n])*de1)<<16);
    *(u32*)&R0[n*136 + t] = bp;
  }
  if (tid<128) ((float*)(Xsh + (tid>>1)*136 + 128))[tid&1] = CUM[(c*CKL+tid)*4 + h];
  __syncthreads();   // bar1
  #define CUMS(t) (((const float*)(Xsh + ((t)>>1)*136 + 128))[(t)&1])

  // ---- phase B: S = xdt^T @ (B*de)^T (LDS) ; CB = C·B^T (global reads) -----
  f32x4 sa[4] = {};
  #pragma unroll
  for (int kt=0; kt<4; kt++){
    half8 aa = *(const half8*)&Xsh[(wid*16+lm)*136 + kt*32 + lq*8];
    #pragma unroll
    for (int nt=0;nt<4;nt++){
      half8 bq = *(const half8*)&R0[(nt*16+lm)*136 + kt*32 + lq*8];
      sa[nt] = __builtin_amdgcn_mfma_f32_16x16x32_f16(aa, bq, sa[nt], 0,0,0);
    }
  }
  #pragma unroll
  for (int nt=0;nt<4;nt++){
    int n = nt*16 + lm;
    #pragma unroll
    for (int r=0;r<4;r++){
      int p = wid*16 + lq*4 + r;
      ST[((c*4+h)*64 + p)*64 + n] = f2h(sa[nt][r]);
    }
  }

  // CB with balanced strips {wid, 7-wid}; operands straight from XB (L1/L2-hot)
  int sp0 = wid, sp1 = 7 - wid;
  f32x4 cbA[4] = {};
  f32x4 cbB[8] = {};
  const u16* lanebase = XBc + lm*CCH + lq*8;
  #pragma unroll
  for (int kt=0; kt<2; kt++){
    half8 afA = *(const half8*)(lanebase + sp0*16*CCH + 320 + kt*32);
    half8 afB = *(const half8*)(lanebase + sp1*16*CCH + 320 + kt*32);
    #pragma unroll
    for (int st=0; st<8; st++){
      if (st <= sp1){
        half8 bq = *(const half8*)(lanebase + st*16*CCH + 256 + kt*32);
        if (st <= sp0)
          cbA[st&3] = __builtin_amdgcn_mfma_f32_16x16x32_f16(afA, bq, cbA[st&3], 0,0,0);
        cbB[st] = __builtin_amdgcn_mfma_f32_16x16x32_f16(afB, bq, cbB[st], 0,0,0);
      }
    }
  }
  __syncthreads();   // bar2: BdeT dead -> Mtri may overlay

  // ---- phase G: per-strip M build (wave-private) + Y_intra; results to regs -
  float dval = Dp[h];
  u16 outv[2][4][4];
  #pragma unroll
  for (int i=0;i<2;i++){
    int sp_ = i ? sp1 : sp0;
    int q = sp_ >> 1;
    int Wst = 32*q + 40;                                  // row width (u16), incl. 8 pad
    int mb  = 16*(32*q*q + 48*q + (sp_&1)*(32*q+40));     // strip base (u16)
    u16* Mrow = Mtri + mb;
    float ct[4];
    #pragma unroll
    for (int r=0;r<4;r++) ct[r] = CUMS(sp_*16 + lq*4 + r);

    // M[t][s] = cb * exp(cum_t - cum_s), lower-triangular
    #pragma unroll
    for (int st=0; st<8; st++){
      if (st <= sp_){
        int s = st*16 + lm;
        float cs = CUMS(s);
        f32x4 cb;
        if (i==0) cb = cbA[st&3]; else cb = cbB[st];
        if (st == sp_){
          #pragma unroll
          for (int r=0;r<4;r++){
            int t = sp_*16 + lq*4 + r;
            float m = (s <= t) ? cb[r]*__expf(ct[r]-cs) : 0.f;
            Mrow[(lq*4+r)*Wst + s] = f2h(m);
          }
          if (!(sp_&1)){   // zero the beyond-diagonal half of the last K=32 tile
            #pragma unroll
            for (int r=0;r<4;r++) Mrow[(lq*4+r)*Wst + s + 16] = 0;
          }
        } else {
          #pragma unroll
          for (int r=0;r<4;r++)
            Mrow[(lq*4+r)*Wst + s] = f2h(cb[r]*__expf(ct[r]-cs));
        }
      }
    }

    // Y_intra = M @ xdt (K tiles up to diagonal)
    f32x4 ya[4] = {};
    int nkt = q + 1;
    #pragma unroll
    for (int kt=0; kt<4; kt++){
      if (kt < nkt){
        half8 af = *(const half8*)&Mrow[lm*Wst + kt*32 + lq*8];
        #pragma unroll
        for (int nt=0;nt<4;nt++){
          half8 bq = *(const half8*)&Xsh[(nt*16+lm)*136 + kt*32 + lq*8];
          ya[nt] = __builtin_amdgcn_mfma_f32_16x16x32_f16(af, bq, ya[nt], 0,0,0);
        }
      }
    }

    // + D*xh, pack fp16 to regs
    #pragma unroll
    for (int nt=0;nt<4;nt++){
      int p = nt*16 + lm;
      #pragma unroll
      for (int r=0;r<4;r++){
        int t = sp_*16 + lq*4 + r;
        float xhv = h2f(XBc[t*CCH + (h<<6) + p]);
        outv[i][nt][r] = f2h(ya[nt][r] + dval*xhv);
      }
    }
  }
  __syncthreads();   // bar3: Xsh/Mtri reads done -> scr overlay

  // ---- phase H: stage [t][p] and write coalesced 128B rows -----------------
  #pragma unroll
  for (int i=0;i<2;i++){
    int sp_ = i ? sp1 : sp0;
    #pragma unroll
    for (int nt=0;nt<4;nt++)
      #pragma unroll
      for (int r=0;r<4;r++)
        scr[(sp_*16+lq*4+r)*68 + nt*16+lm] = outv[i][nt][r];
  }
  __syncthreads();   // bar4
  for (int idx=tid; idx<2048; idx+=256){
    int row = idx>>4, q = idx&15;
    *(uint2*)(YA + ((c*CKL+row)<<8) + (h<<6) + q*4) = *(const uint2*)(&scr[row*68 + q*4]);
  }
  #undef CUMS
}

// ---------------- K5: block-local segmented scan ----------------------------
__global__ __launch_bounds__(256) void k_scan(const u16* __restrict__ ST, u16* __restrict__ HP,
                                              const float* __restrict__ CDEC){
  __shared__ float L[4][64][64];   // 65536 B local prefixes
  __shared__ float E[4][64];       // segment-end values
  int tid = threadIdx.x;
  int j = tid>>6, s = tid&63;
  int b = blockIdx.x;
  int g = b*64 + s;
  int h = g>>12;
  int a = j*64;
  float hloc = 0.f;
  #pragma unroll 16
  for (int i=0;i<64;i++){
    int c = a+i;
    L[j][i][s] = hloc;
    hloc = CDEC[(c<<2)+h]*hloc + h2f(ST[g + (c<<14)]);
  }
  E[j][s] = hloc;
  __syncthreads();
  float carry = 0.f;
  for (int k=0;k<j;k++){           // wave-uniform trip count (j = wave id)
    float P = 1.f;
    #pragma unroll 16
    for (int i=0;i<64;i++) P *= CDEC[((k*64+i)<<2)+h];
    carry = E[k][s] + P*carry;
  }
  float m = 1.f;
  #pragma unroll 16
  for (int i=0;i<64;i++){
    int c = a+i;
    HP[g + (c<<14)] = f2h(L[j][i][s] + m*carry);
    m *= CDEC[(c<<2)+h];
  }
}

// -------- K6: YB = exp(cum[t,h]) * C·H^T — 64-row t-tiles (grid 512) --------
// LDS ~47KB -> 3 blocks/CU capacity, 2 resident (was 1 at 128-row tiles).
__global__ __launch_bounds__(256) void k_inter(const u16* __restrict__ XB, const float* __restrict__ CUM,
                                               const u16* __restrict__ HP, u16* __restrict__ YB){
  __shared__ u16 Cs[64*72];
  __shared__ u16 Hs[4*64*72];
  __shared__ float ex_s[4*64];
  int c = blockIdx.x>>1, hf = blockIdx.x&1;
  int tb = hf*64;
  int tid = threadIdx.x, lane = tid&63, wid = tid>>6;
  int lm = lane&15, lq = lane>>4;
  for (int idx=tid; idx<512; idx+=256){
    int t = idx>>3, b8 = idx&7;
    *(uint4*)&Cs[t*72 + b8*8] = *(const uint4*)(XB + (c*CKL+tb+t)*CCH + 320 + b8*8);
  }
  for (int idx=tid; idx<2048; idx+=256){
    int h = idx>>9, p = (idx>>3)&63, b8 = idx&7;
    *(uint4*)&Hs[(h*64+p)*72 + b8*8] = *(const uint4*)(HP + ((c*4+h)*64+p)*64 + b8*8);
  }
  {
    int h = tid>>6, t = tid&63;
    ex_s[h*64+t] = __expf(CUM[(c*CKL+tb+t)*4+h]);
  }
  __syncthreads();
  int h = wid;
  const u16* Hh = &Hs[h*64*72];
  f32x4 acc[4][4] = {};
  for (int kt=0; kt<2; kt++){
    half8 af[4], bfv[4];
    #pragma unroll
    for (int mt=0;mt<4;mt++) af[mt] = *(const half8*)&Cs[(mt*16+lm)*72 + kt*32 + lq*8];
    #pragma unroll
    for (int nt=0;nt<4;nt++) bfv[nt] = *(const half8*)&Hh[(nt*16+lm)*72 + kt*32 + lq*8];
    #pragma unroll
    for (int mt=0;mt<4;mt++)
      #pragma unroll
      for (int nt=0;nt<4;nt++)
        acc[mt][nt] = __builtin_amdgcn_mfma_f32_16x16x32_f16(af[mt], bfv[nt], acc[mt][nt], 0,0,0);
  }
  #pragma unroll
  for (int mt=0;mt<4;mt++){
    #pragma unroll
    for (int r=0;r<4;r++){
      int t = mt*16 + lq*4 + r;
      float e = ex_s[h*64+t];
      u16* dst = &YB[((c*CKL+tb+t)<<8) + (h<<6)];
      #pragma unroll
      for (int nt=0;nt<4;nt++){
        int p = nt*16 + lm;
        dst[p] = f2h(e*acc[mt][nt][r]);
      }
    }
  }
}

// -------- K7: fused ynorm + out GEMM + gate scatter — 64-row tiles (512) ----
// LDS ~52.5KB -> 3 blocks/CU capacity, 2 resident. Per-wave: 16 rows, acc[8].
__global__ __launch_bounds__(256) void k_gout_mfma(const u16* __restrict__ YA, const u16* __restrict__ YB,
                                                   const u16* __restrict__ ZX, const float* __restrict__ nw,
                                                   const u16* __restrict__ WoT,
                                                   const float* __restrict__ G, float* __restrict__ GACC, int run){
  __shared__ u16 Ys[64*136];
  __shared__ u16 Ws[128*136];
  __shared__ float SSs[64];
  int t0 = blockIdx.x*64;
  int tid = threadIdx.x, lane = tid&63, wid = tid>>6;
  int lm = lane&15, lq = lane>>4;
  f32x4 acc[8] = {};
  for (int kb=0; kb<2; kb++){
    __syncthreads();
    for (int ch=tid; ch<1024; ch+=256){
      int row = ch>>4, c8 = ch&15;
      int t = t0+row;
      int cb = kb*128 + c8*8;
      uint2 av0 = *(const uint2*)(YA + t*DIN + cb);
      uint2 av1 = *(const uint2*)(YA + t*DIN + cb + 4);
      uint2 bv0 = *(const uint2*)(YB + t*DIN + cb);
      uint2 bv1 = *(const uint2*)(YB + t*DIN + cb + 4);
      uint2 zv0 = *(const uint2*)(ZX + t*ZXS + cb);
      uint2 zv1 = *(const uint2*)(ZX + t*ZXS + cb + 4);
      float af[8], bf[8], zf[8];
      up4(av0, af); up4(av1, af+4);
      up4(bv0, bf); up4(bv1, bf+4);
      up4(zv0, zf); up4(zv1, zf+4);
      float ssp = 0.f;
      union { uint4 u; u16 h[8]; } pk;
      #pragma unroll
      for (int j=0;j<8;j++){
        float u = (af[j]+bf[j])*siluf_(zf[j]);
        ssp += u*u;
        pk.h[j] = f2h(u*nw[cb+j]);
      }
      *(uint4*)&Ys[row*136 + c8*8] = pk.u;
      #pragma unroll
      for (int off=1; off<16; off<<=1) ssp += __shfl_xor(ssp, off, 64);
      if ((lane&15)==0){ if (kb==0) SSs[row] = ssp; else SSs[row] += ssp; }
    }
    for (int ch=tid; ch<2048; ch+=256){
      int row = ch>>4, c8 = ch&15;
      *(uint4*)&Ws[row*136 + c8*8] = *(const uint4*)(WoT + row*DIN + kb*128 + c8*8);
    }
    __syncthreads();
    for (int kt=0; kt<4; kt++){
      half8 af = *(const half8*)&Ys[(wid*16+lm)*136 + kt*32 + lq*8];
      half8 bfv[8];
      #pragma unroll
      for (int nt=0;nt<8;nt++) bfv[nt] = *(const half8*)&Ws[(nt*16+lm)*136 + kt*32 + lq*8];
      #pragma unroll
      for (int nt=0;nt<8;nt++)
        acc[nt] = __builtin_amdgcn_mfma_f32_16x16x32_f16(af, bfv[nt], acc[nt], 0,0,0);
    }
  }
  #pragma unroll
  for (int r=0;r<4;r++){
    int tl = wid*16 + lq*4 + r;
    int t = t0 + tl;
    int sp = seq2sp(t, run);
    float sc = rsqrtf(SSs[tl]*(1.f/DIN)+1e-6f);
    float g = G[run*LSEQ + sp] * sc;
    float* dst = &GACC[sp*CDIM];
    if (run==0){
      #pragma unroll
      for (int nt=0;nt<8;nt++) dst[nt*16+lm] = g*acc[nt][r];
    } else {
      #pragma unroll
      for (int nt=0;nt<8;nt++) dst[nt*16+lm] += g*acc[nt][r];
    }
  }
}

// ---------------- K8: depthwise 3x3x3 conv, LDS-tiled -----------------------
__global__ __launch_bounds__(256) void k_dwconv(const float* __restrict__ XN, const float* __restrict__ w,
                                                const float* __restrict__ b, float* __restrict__ LC1){
  __shared__ float sm[3*34*40];
  int cc = blockIdx.x>>5, d = blockIdx.x&31;
  int tid = threadIdx.x;
  for (int i=tid; i<4080; i+=256) sm[i] = 0.f;
  __syncthreads();
  #pragma unroll
  for (int p=0;p<3;p++){
    int dz = d-1+p;
    if ((unsigned)dz<=31u){
      for (int idx=tid; idx<1024; idx+=256){
        int hh = idx>>5, ww = idx&31;
        sm[p*1360 + (hh+1)*40 + (ww+4)] = XN[cc*LSEQ + (dz<<10) + idx];
      }
    }
  }
  __syncthreads();
  float wreg[27];
  #pragma unroll
  for (int i=0;i<27;i++) wreg[i] = w[cc*27+i];
  float bias = b[cc];
  int h = tid>>3, w0 = (tid&7)*4;
  float4 acc = {bias,bias,bias,bias};
  #pragma unroll
  for (int p=0;p<3;p++){
    #pragma unroll
    for (int dy=0;dy<3;dy++){
      const float* row = &sm[p*1360 + (h+dy)*40 + 4];
      float left  = row[w0-1];
      float4 mid  = *(const float4*)&row[w0];
      float right = row[w0+4];
      float wa=wreg[p*9+dy*3+0], wb=wreg[p*9+dy*3+1], wc=wreg[p*9+dy*3+2];
      acc.x += wa*left  + wb*mid.x + wc*mid.y;
      acc.y += wa*mid.x + wb*mid.y + wc*mid.z;
      acc.z += wa*mid.y + wb*mid.z + wc*mid.w;
      acc.w += wa*mid.z + wb*mid.w + wc*right;
    }
  }
  *(float4*)&LC1[cc*LSEQ + (d<<10) + h*32 + w0] = acc;
}

// ---------------- K9: pointwise 128x128 + silu (fp16 MFMA) ------------------
__global__ __launch_bounds__(256) void k_pw(const float* __restrict__ LC1, const float* __restrict__ pw,
                                            const float* __restrict__ pwb, float* __restrict__ LC2){
  __shared__ u16 Ws[128*136];
  __shared__ u16 Bs[128*136];
  int s0 = blockIdx.x*128;
  int tid = threadIdx.x, lane = tid&63, wid = tid>>6;
  int lm = lane&15, lq = lane>>4;
  for (int idx=tid; idx<16384; idx+=256){
    int o = idx>>7, cc = idx&127;
    Ws[o*136+cc] = f2h(pw[idx]);
  }
  for (int idx=tid; idx<16384; idx+=256){
    int cc = idx>>7, n = idx&127;
    Bs[n*136+cc] = f2h(LC1[cc*LSEQ + s0 + n]);
  }
  __syncthreads();
  f32x4 acc[2][8] = {};
  for (int kt=0; kt<4; kt++){
    half8 af[2], bfv[8];
    #pragma unroll
    for (int mt=0;mt<2;mt++) af[mt] = *(const half8*)&Ws[(wid*32+mt*16+lm)*136 + kt*32 + lq*8];
    #pragma unroll
    for (int nt=0;nt<8;nt++) bfv[nt] = *(const half8*)&Bs[(nt*16+lm)*136 + kt*32 + lq*8];
    #pragma unroll
    for (int mt=0;mt<2;mt++)
      #pragma unroll
      for (int nt=0;nt<8;nt++)
        acc[mt][nt] = __builtin_amdgcn_mfma_f32_16x16x32_f16(af[mt], bfv[nt], acc[mt][nt], 0,0,0);
  }
  #pragma unroll
  for (int mt=0;mt<2;mt++){
    #pragma unroll
    for (int r=0;r<4;r++){
      int o = wid*32 + mt*16 + lq*4 + r;
      float bb = pwb[o];
      float* dst = &LC2[o*LSEQ + s0];
      #pragma unroll
      for (int nt=0;nt<8;nt++){
        int n = nt*16 + lm;
        dst[n] = siluf_(acc[mt][nt][r] + bb);
      }
    }
  }
}

// -------- K10: fused = a*g + (1-a)*lc, transpose + per-block mean partials --
__global__ void k_fuse(const float* __restrict__ GACC, const float* __restrict__ LC2,
                       const float* __restrict__ alpha, float* __restrict__ FUSED,
                       float* __restrict__ MEANP){
  __shared__ float tile[64*65];
  int bs = blockIdx.x>>1, bc = blockIdx.x&1;
  int s0 = bs*64, c0 = bc*64;
  int tid = threadIdx.x;
  float a = alpha[0];
  for (int idx=tid; idx<4096; idx+=256){
    int i = idx>>6, j = idx&63;
    tile[i*65+j] = GACC[(s0+i)*CDIM + c0+j];
  }
  __syncthreads();
  for (int idx=tid; idx<4096; idx+=256){
    int j = idx>>6, i = idx&63;   // j wave-uniform; i = lane
    float g = tile[i*65+j];
    float l = LC2[(c0+j)*LSEQ + s0+i];
    float f = a*g + (1.f-a)*l;
    FUSED[(c0+j)*LSEQ + s0+i] = f;
    float wsum = f;
    #pragma unroll
    for (int off=32; off; off>>=1) wsum += __shfl_xor(wsum, off, 64);
    if ((tid&63)==0) MEANP[(c0+j)*512 + bs] = wsum;
  }
}

// ---------------- K11: channel attention (reduces MEANP partials) -----------
__global__ void k_ca(const float* __restrict__ MEANP, const float* __restrict__ w1, const float* __restrict__ b1,
                     const float* __restrict__ w2, const float* __restrict__ b2, float* __restrict__ SIG){
  __shared__ float MEANsh[128];
  __shared__ float y1[8];
  int tid = threadIdx.x;
  {
    float acc = 0.f;
    const float* p = MEANP + tid*512;
    #pragma unroll 16
    for (int b=0;b<512;b++) acc += p[b];
    MEANsh[tid] = acc*(1.f/LSEQ);
  }
  __syncthreads();
  if (tid<8){
    float acc = b1[tid];
    for (int c=0;c<128;c++) acc += w1[tid*128+c]*MEANsh[c];
    y1[tid] = (acc>=0.f)? acc : 0.1f*acc;
  }
  __syncthreads();
  float acc = b2[tid];
  #pragma unroll
  for (int o=0;o<8;o++) acc += w2[tid*8+o]*y1[o];
  SIG[tid] = sigmoidf_(acc);
}

// ---------------- K12: out = x + fused * sigmoid(yc) ------------------------
__global__ void k_final(const float* __restrict__ x, const float* __restrict__ F, const float* __restrict__ SIG,
                        float* __restrict__ out){
  int idx = blockIdx.x*256 + threadIdx.x;
  int cc = idx>>15;
  out[idx] = x[idx] + F[idx]*SIG[cc];
}

extern "C" void kernel_launch(void* const* d_in, const int* in_sizes, int n_in,
                              void* d_out, int out_size, void* d_ws, size_t ws_size,
                              hipStream_t stream){
  (void)in_sizes; (void)n_in; (void)out_size; (void)ws_size;
  const float* x       = (const float*)d_in[0];
  const float* norm_w  = (const float*)d_in[1];
  const float* gate_w  = (const float*)d_in[2];
  const float* gate_b  = (const float*)d_in[3];
  const float* loc_dw_w= (const float*)d_in[28];
  const float* loc_dw_b= (const float*)d_in[29];
  const float* loc_pw_w= (const float*)d_in[30];
  const float* loc_pw_b= (const float*)d_in[31];
  const float* ca_w1   = (const float*)d_in[32];
  const float* ca_b1   = (const float*)d_in[33];
  const float* ca_w2   = (const float*)d_in[34];
  const float* ca_b2   = (const float*)d_in[35];
  const float* alpha   = (const float*)d_in[36];

  float* W     = (float*)d_ws;
  float* XN    = W;                         // 4,194,304
  float* GATES = XN    + 4194304;           //   196,608
  float* GACC  = GATES + 196608;            // 4,194,304
  u16*   ZX    = (u16*)(GACC + 4194304);    // 22,020,096 u16 (stride 672)
  u16*   XB    = (u16*)(GACC + 4194304 + 11010048);   // 12,582,912 u16
  float* DT    = GACC + 4194304 + 11010048 + 6291456; // 131,072
  float* CUM   = DT    + 131072;            //   131,072
  float* CDEC  = CUM   + 131072;            //     1,024
  float* DE    = CDEC  + 1024;              //   131,072
  float* STreg = DE    + 131072;            // 4,194,304 fl region (ST16)
  float* Y     = STreg + 4194304;           // 8,388,608 fl = YA/YB fp16
  float* LC1   = Y     + 8388608;           // 4,194,304 (HPREV16 alias)
  float* LC2   = LC1   + 4194304;           // 4,194,304
  float* MEANP = LC2   + 4194304;           //    65,536
  float* SIG   = MEANP + 65536;             //       128
  u16*   XNT   = (u16*)(SIG + 128);         // 4,194,304 u16
  u16*   WinT  = XNT + 4194304;             //    98,304 u16
  u16*   WoT   = WinT + 98304;              //    32,768 u16
  u16*   ST16  = (u16*)STreg;               // 4,194,304 u16
  u16*   YA    = (u16*)Y;                   // 8,388,608 u16
  u16*   YB    = YA + 8388608;              // 8,388,608 u16
  u16*   HP16  = (u16*)LC1;                 // 4,194,304 u16

  k_xn<<<128,256,0,stream>>>(x, norm_w, gate_w, gate_b, XN, GATES);

  for (int r=0;r<6;r++){
    int m = r>>1;
    const float* Win   = (const float*)d_in[4 + m*8 + 0];
    const float* convw = (const float*)d_in[4 + m*8 + 1];
    const float* convb = (const float*)d_in[4 + m*8 + 2];
    const float* dtb   = (const float*)d_in[4 + m*8 + 3];
    const float* Alog  = (const float*)d_in[4 + m*8 + 4];
    const float* Dp    = (const float*)d_in[4 + m*8 + 5];
    const float* nw2   = (const float*)d_in[4 + m*8 + 6];
    const float* Wout  = (const float*)d_in[4 + m*8 + 7];
    if ((r&1)==0){
      k_permprep<<<1536,256,0,stream>>>(XN, XNT, m, Win, Wout, WinT, WoT);
    }
    k_gin_mfma<<<1536,256,0,stream>>>(XNT, WinT, ZX, r&1);
    k_convdt  <<<1280,384,0,stream>>>(ZX, convw, convb, XB, dtb, Alog, DT, CUM, CDEC, DE);
    k_chunk   <<<1024,256,0,stream>>>(XB, DT, CUM, DE, Dp, YA, ST16);
    k_scan    <<<256,256,0,stream>>>(ST16, HP16, CDEC);
    k_inter   <<<512,256,0,stream>>>(XB, CUM, HP16, YB);
    k_gout_mfma<<<512,256,0,stream>>>(YA, YB, ZX, nw2, WoT, GATES, GACC, r);
  }

  k_dwconv<<<4096,256,0,stream>>>(XN, loc_dw_w, loc_dw_b, LC1);
  k_pw    <<<256,256,0,stream>>>(LC1, loc_pw_w, loc_pw_b, LC2);
  k_fuse  <<<1024,256,0,stream>>>(GACC, LC2, alpha, LC1, MEANP);
  k_ca    <<<1,128,0,stream>>>(MEANP, ca_w1, ca_b1, ca_w2, ca_b2, SIG);
  k_final <<<16384,256,0,stream>>>(x, LC1, SIG, (float*)d_out);
}